// Round 10
// baseline (247.628 us; speedup 1.0000x reference)
//
#include <hip/hip_runtime.h>
#include <stdint.h>

#define B_ 8
#define N_ 2048
#define D_ 768

typedef unsigned short u16;
typedef unsigned char u8;
typedef unsigned int u32;
typedef __attribute__((ext_vector_type(8))) short bf16x8;
typedef __attribute__((ext_vector_type(8))) unsigned short u16x8;
typedef __attribute__((ext_vector_type(4))) float f32x4;

static constexpr float INV_SCALE = 0.10825317547305482f; // 3/sqrt(768)
static constexpr float VS_SCALE = 4096.0f;               // Vs fp8 range scale

__device__ __forceinline__ u16 f2bf(float f) {
  union { float f; unsigned u; } v; v.f = f;
  return (u16)((v.u + 0x7FFFu + ((v.u >> 16) & 1u)) >> 16);
}
__device__ __forceinline__ float bf2f(u16 h) {
  union { unsigned u; float f; } v; v.u = ((unsigned)h) << 16;
  return v.f;
}
// OCP e4m3fn encode: RNE to 3-bit mantissa, clamp 448, FTZ below 2^-6.
__device__ __forceinline__ u8 f2fp8(float f) {
  union { float f; u32 u; } v; v.f = f;
  u32 s = (v.u >> 24) & 0x80u;
  u32 m = v.u & 0x7fffffffu;
  if (m >= 0x43E00000u) return (u8)(s | 0x7Eu);   // clamp to 448
  if (m < 0x3C800000u) return (u8)s;              // FTZ below 2^-6
  m += 0x000FFFFFu + ((m >> 20) & 1u);            // RNE at bit 20
  int e = (int)(m >> 23) - 127;
  if (e > 8) return (u8)(s | 0x7Eu);
  return (u8)(s | ((u32)(e + 7) << 3) | ((m >> 20) & 7u));
}
__device__ __forceinline__ f32x4 mfma16(bf16x8 a, bf16x8 b, f32x4 c) {
  return __builtin_amdgcn_mfma_f32_16x16x32_bf16(a, b, c, 0, 0, 0);
}
__device__ __forceinline__ f32x4 mfma8(long a, long b, f32x4 c) {
  return __builtin_amdgcn_mfma_f32_16x16x32_fp8_fp8(a, b, c, 0, 0, 0);
}
__device__ __forceinline__ void gl_lds16(const void* g, void* l) {
  __builtin_amdgcn_global_load_lds(
      (const __attribute__((address_space(1))) u32*)g,
      (__attribute__((address_space(3))) u32*)l, 16, 0, 0);
}

// ---------------- K0: cast x, Wq, Wk, Wv to bf16 ----------------
__global__ __launch_bounds__(256) void cast_kernel(
    const float* __restrict__ x, const float* __restrict__ wq,
    const float* __restrict__ wk, const float* __restrict__ wv,
    u16* __restrict__ xb, u16* __restrict__ wqb,
    u16* __restrict__ wkb, u16* __restrict__ wvb) {
  const long NX = (long)B_ * N_ * D_;
  const long NW = (long)D_ * D_;
  long i = ((long)blockIdx.x * 256 + threadIdx.x) * 8;
  const float* src; u16* dst; long off;
  if (i < NX) { src = x; dst = xb; off = i; }
  else {
    long j = i - NX;
    int seg = (int)(j / NW);
    off = j - (long)seg * NW;
    src = seg == 0 ? wq : (seg == 1 ? wk : wv);
    dst = seg == 0 ? wqb : (seg == 1 ? wkb : wvb);
  }
  float4 a = *(const float4*)(src + off);
  float4 b = *(const float4*)(src + off + 4);
  u16x8 o;
  o[0]=f2bf(a.x); o[1]=f2bf(a.y); o[2]=f2bf(a.z); o[3]=f2bf(a.w);
  o[4]=f2bf(b.x); o[5]=f2bf(b.y); o[6]=f2bf(b.z); o[7]=f2bf(b.w);
  *(u16x8*)(dst + off) = o;
}

// ==== bf16 256x256 BK=64 core (R9, unchanged): 8 waves, wave tile 128x64 ====
template<int NT>
__device__ __forceinline__ void gemm256(
    const u16* __restrict__ Ag, long lda,
    const u16* __restrict__ Bg, long ldb,
    f32x4 (&acc)[8][4]) {
  __shared__ u16 Ab[2][16384];
  __shared__ u16 Bb[2][16384];
  const int t_ = threadIdx.x, l = t_ & 63, w = t_ >> 6;
  const int lr = l & 15, kq = l >> 4;
  const int wm = w >> 2, wn = w & 3;
  const int arow = wm * 128, brow = wn * 64;
  const int s_rowl = l >> 3;
  const int s_sl = (l & 7) ^ (l >> 3);
  auto STAGE_A = [&](u16* As, int kt) {
    #pragma unroll
    for (int j = 0; j < 4; ++j) {
      const int row = j * 64 + w * 8 + s_rowl;
      gl_lds16(Ag + (long)row * lda + kt * 64 + s_sl * 8,
               As + ((j * 8192 + w * 1024) >> 1));
    }
  };
  auto STAGE_B = [&](u16* Bs, int kt) {
    #pragma unroll
    for (int j = 0; j < 4; ++j) {
      const int row = j * 64 + w * 8 + s_rowl;
      gl_lds16(Bg + (long)row * ldb + kt * 64 + s_sl * 8,
               Bs + ((j * 8192 + w * 1024) >> 1));
    }
  };

#define TILE(XA, XB, YA, YB, kt, DOST)                                       \
  {                                                                          \
    if (DOST) {                                                              \
      STAGE_A(YA, (kt) + 1);                                                 \
      asm volatile("s_waitcnt vmcnt(4)" ::: "memory");                       \
    } else {                                                                 \
      asm volatile("s_waitcnt vmcnt(0)" ::: "memory");                       \
    }                                                                        \
    __builtin_amdgcn_s_barrier();                                            \
    asm volatile("" ::: "memory");                                           \
    bf16x8 bf[4][2];                                                         \
    _Pragma("unroll")                                                        \
    for (int nf = 0; nf < 4; ++nf) {                                         \
      const int row = brow + nf * 16 + lr;                                   \
      _Pragma("unroll")                                                      \
      for (int ks = 0; ks < 2; ++ks)                                         \
        bf[nf][ks] = *(const bf16x8*)(XB + row * 64 +                        \
                        (((4 * ks + kq) ^ (lr & 7)) * 8));                   \
    }                                                                        \
    {                                                                        \
      bf16x8 af[4][2];                                                       \
      _Pragma("unroll")                                                      \
      for (int mf = 0; mf < 4; ++mf) {                                       \
        const int row = arow + mf * 16 + lr;                                 \
        _Pragma("unroll")                                                    \
        for (int ks = 0; ks < 2; ++ks)                                       \
          af[mf][ks] = *(const bf16x8*)(XA + row * 64 +                      \
                          (((4 * ks + kq) ^ (lr & 7)) * 8));                 \
      }                                                                      \
      __builtin_amdgcn_s_setprio(1);                                         \
      _Pragma("unroll")                                                      \
      for (int ks = 0; ks < 2; ++ks)                                         \
        _Pragma("unroll")                                                    \
        for (int mf = 0; mf < 4; ++mf)                                       \
          _Pragma("unroll")                                                  \
          for (int nf = 0; nf < 4; ++nf)                                     \
            acc[mf][nf] = mfma16(af[mf][ks], bf[nf][ks], acc[mf][nf]);       \
      __builtin_amdgcn_s_setprio(0);                                         \
    }                                                                        \
    if (DOST) STAGE_B(YB, (kt) + 1);                                         \
    {                                                                        \
      bf16x8 af[4][2];                                                       \
      _Pragma("unroll")                                                      \
      for (int mf = 0; mf < 4; ++mf) {                                       \
        const int row = arow + 64 + mf * 16 + lr;                            \
        _Pragma("unroll")                                                    \
        for (int ks = 0; ks < 2; ++ks)                                       \
          af[mf][ks] = *(const bf16x8*)(XA + row * 64 +                      \
                          (((4 * ks + kq) ^ (lr & 7)) * 8));                 \
      }                                                                      \
      __builtin_amdgcn_s_setprio(1);                                         \
      _Pragma("unroll")                                                      \
      for (int ks = 0; ks < 2; ++ks)                                         \
        _Pragma("unroll")                                                    \
        for (int mf = 0; mf < 4; ++mf)                                       \
          _Pragma("unroll")                                                  \
          for (int nf = 0; nf < 4; ++nf)                                     \
            acc[4 + mf][nf] = mfma16(af[mf][ks], bf[nf][ks], acc[4 + mf][nf]); \
      __builtin_amdgcn_s_setprio(0);                                         \
    }                                                                        \
    asm volatile("" ::: "memory");                                           \
    __builtin_amdgcn_s_barrier();                                            \
  }

  STAGE_A(Ab[0], 0);
  STAGE_B(Bb[0], 0);
  for (int t2 = 0; t2 < NT; t2 += 2) {
    TILE(Ab[0], Bb[0], Ab[1], Bb[1], t2, true)
    TILE(Ab[1], Bb[1], Ab[0], Bb[0], t2 + 1, (t2 + 2 < NT))
  }
#undef TILE
}

// ==== fp8 256x256 BK=64 core: 8 waves, wave tile 128x64 ====
// LDS tile [256 rows][64 B]; swizzle on 16B slots: phys16 = s16 ^ (row&3),
// gl_lds-compatible both sides (source pre-swizzled per 16B block).
// Fragments: b64 reads (8 fp8 = K-slice of one 16x16x32 fp8 MFMA).
// Residual 4-way bank conflict on reads (rows ≡ mod 4) — 1.58x on half bytes.
template<int NT>
__device__ __forceinline__ void gemm256_fp8(
    const u8* __restrict__ Ag, long lda,
    const u8* __restrict__ Bg, long ldb,
    f32x4 (&acc)[8][4]) {
  __shared__ u8 Ab[2][16384];
  __shared__ u8 Bb[2][16384];
  const int t_ = threadIdx.x, l = t_ & 63, w = t_ >> 6;
  const int lr = l & 15, kq = l >> 4;
  const int wm = w >> 2, wn = w & 3;
  const int arow = wm * 128, brow = wn * 64;
  // staging: chunk ch = w*2+c covers rows [16ch,16ch+16); lane l writes
  // row 16ch + (l>>2), phys s16 = l&3; source s16 = (l&3) ^ ((l>>2)&3)
  const int srow_l = l >> 2;
  const int s16src = (l & 3) ^ ((l >> 2) & 3);
  auto STAGE_A = [&](u8* As, int kt) {
    #pragma unroll
    for (int c = 0; c < 2; ++c) {
      const int ch = w * 2 + c;
      gl_lds16(Ag + (long)(ch * 16 + srow_l) * lda + kt * 64 + s16src * 16,
               As + ch * 1024);
    }
  };
  auto STAGE_B = [&](u8* Bs, int kt) {
    #pragma unroll
    for (int c = 0; c < 2; ++c) {
      const int ch = w * 2 + c;
      gl_lds16(Bg + (long)(ch * 16 + srow_l) * ldb + kt * 64 + s16src * 16,
               Bs + ch * 1024);
    }
  };
  // fragment byte addr: row*64 + ((k8>>1)^(row&3))*16 + (k8&1)*8, k8=4ks+kq
#define FR8(BASE, ROW, KS)                                                   \
  (*(const long*)((BASE) + (ROW) * 64 +                                      \
      ((((4 * (KS) + kq) >> 1) ^ ((ROW) & 3)) * 16) + ((4 * (KS) + kq) & 1) * 8))

#define TILE8(XA, XB, YA, YB, kt, DOST)                                      \
  {                                                                          \
    if (DOST) {                                                              \
      STAGE_A(YA, (kt) + 1);                                                 \
      asm volatile("s_waitcnt vmcnt(2)" ::: "memory");                       \
    } else {                                                                 \
      asm volatile("s_waitcnt vmcnt(0)" ::: "memory");                       \
    }                                                                        \
    __builtin_amdgcn_s_barrier();                                            \
    asm volatile("" ::: "memory");                                           \
    long bfr[4][2];                                                          \
    _Pragma("unroll")                                                        \
    for (int nf = 0; nf < 4; ++nf) {                                         \
      const int row = brow + nf * 16 + lr;                                   \
      _Pragma("unroll")                                                      \
      for (int ks = 0; ks < 2; ++ks)                                         \
        bfr[nf][ks] = FR8(XB, row, ks);                                      \
    }                                                                        \
    {                                                                        \
      long afr[4][2];                                                        \
      _Pragma("unroll")                                                      \
      for (int mf = 0; mf < 4; ++mf) {                                       \
        const int row = arow + mf * 16 + lr;                                 \
        _Pragma("unroll")                                                    \
        for (int ks = 0; ks < 2; ++ks)                                       \
          afr[mf][ks] = FR8(XA, row, ks);                                    \
      }                                                                      \
      __builtin_amdgcn_s_setprio(1);                                         \
      _Pragma("unroll")                                                      \
      for (int ks = 0; ks < 2; ++ks)                                         \
        _Pragma("unroll")                                                    \
        for (int mf = 0; mf < 4; ++mf)                                       \
          _Pragma("unroll")                                                  \
          for (int nf = 0; nf < 4; ++nf)                                     \
            acc[mf][nf] = mfma8(afr[mf][ks], bfr[nf][ks], acc[mf][nf]);      \
      __builtin_amdgcn_s_setprio(0);                                         \
    }                                                                        \
    if (DOST) STAGE_B(YB, (kt) + 1);                                         \
    {                                                                        \
      long afr[4][2];                                                        \
      _Pragma("unroll")                                                      \
      for (int mf = 0; mf < 4; ++mf) {                                       \
        const int row = arow + 64 + mf * 16 + lr;                            \
        _Pragma("unroll")                                                    \
        for (int ks = 0; ks < 2; ++ks)                                       \
          afr[mf][ks] = FR8(XA, row, ks);                                    \
      }                                                                      \
      __builtin_amdgcn_s_setprio(1);                                         \
      _Pragma("unroll")                                                      \
      for (int ks = 0; ks < 2; ++ks)                                         \
        _Pragma("unroll")                                                    \
        for (int mf = 0; mf < 4; ++mf)                                       \
          _Pragma("unroll")                                                  \
          for (int nf = 0; nf < 4; ++nf)                                     \
            acc[4 + mf][nf] = mfma8(afr[mf][ks], bfr[nf][ks], acc[4 + mf][nf]); \
      __builtin_amdgcn_s_setprio(0);                                         \
    }                                                                        \
    asm volatile("" ::: "memory");                                           \
    __builtin_amdgcn_s_barrier();                                            \
  }

  STAGE_A(Ab[0], 0);
  STAGE_B(Bb[0], 0);
  for (int t2 = 0; t2 < NT; t2 += 2) {
    TILE8(Ab[0], Bb[0], Ab[1], Bb[1], t2, true)
    TILE8(Ab[1], Bb[1], Ab[0], Bb[0], t2 + 1, (t2 + 2 < NT))
  }
#undef TILE8
#undef FR8
}

// ---------------- K1: Q/K/V = x @ W^T + b (Q scaled) ----------------
__global__ __launch_bounds__(512, 2) void qkv_gemm(
    const u16* __restrict__ xb,
    const u16* __restrict__ wq, const u16* __restrict__ wk, const u16* __restrict__ wv,
    const float* __restrict__ bq, const float* __restrict__ bk, const float* __restrict__ bv,
    u16* __restrict__ Qs, u16* __restrict__ Kb, u16* __restrict__ Vb) {
  const int lin = blockIdx.x;
  const int xcd = lin & 7, inner = lin >> 3;
  const int rt = xcd * 8 + (inner & 7);
  const int rest = inner >> 3;
  const int ct = rest % 3, mat = rest / 3;
  const u16* W = mat == 0 ? wq : (mat == 1 ? wk : wv);
  const float* bias = mat == 0 ? bq : (mat == 1 ? bk : bv);
  u16* out = mat == 0 ? Qs : (mat == 1 ? Kb : Vb);
  const float scl = mat == 0 ? INV_SCALE : 1.0f;
  const int rbase = rt * 256, cbase = ct * 256;

  f32x4 acc[8][4] = {};
  gemm256<D_ / 64>(xb + (long)rbase * D_, D_, W + (long)cbase * D_, D_, acc);

  const int l = threadIdx.x & 63, w = threadIdx.x >> 6;
  const int lr = l & 15, orow = (l >> 4) * 4;
  const int wm = w >> 2, wn = w & 3;
  #pragma unroll
  for (int mf = 0; mf < 8; ++mf)
    #pragma unroll
    for (int nf = 0; nf < 4; ++nf) {
      int col = cbase + wn * 64 + nf * 16 + lr;
      float bc = bias[col];
      #pragma unroll
      for (int r = 0; r < 4; ++r) {
        int row = rbase + wm * 128 + mf * 16 + orow + r;
        out[(long)row * D_ + col] = f2bf((acc[mf][nf][r] + bc) * scl);
      }
    }
}

// ---------------- K2: P8 = fp8(exp(Q.K^T)), den partials ----------------
__global__ __launch_bounds__(512, 2) void qk_exp(
    const u16* __restrict__ Qs, const u16* __restrict__ Kb,
    u8* __restrict__ P8, float* __restrict__ denpart) {
  const int lin = blockIdx.x;
  const int b = lin & 7, inner = lin >> 3;
  const int kblk = inner & 7, qblk = inner >> 3;

  f32x4 acc[8][4] = {};
  gemm256<D_ / 64>(Qs + ((long)b * N_ + qblk * 256) * D_, D_,
                   Kb + ((long)b * N_ + kblk * 256) * D_, D_, acc);

  const int tt = threadIdx.x, l = tt & 63, w = tt >> 6;
  const int lr = l & 15, orow = (l >> 4) * 4;
  const int wm = w >> 2, wn = w & 3;
  float csum[4] = {0.f, 0.f, 0.f, 0.f};
  #pragma unroll
  for (int mf = 0; mf < 8; ++mf)
    #pragma unroll
    for (int nf = 0; nf < 4; ++nf) {
      long kk = kblk * 256 + wn * 64 + nf * 16 + lr;
      #pragma unroll
      for (int r = 0; r < 4; ++r) {
        long q = qblk * 256 + wm * 128 + mf * 16 + orow + r;
        float e = __expf(acc[mf][nf][r]);
        P8[((long)b * N_ + q) * N_ + kk] = f2fp8(e);
        csum[nf] += e;
      }
    }
  #pragma unroll
  for (int nf = 0; nf < 4; ++nf) {
    csum[nf] += __shfl_xor(csum[nf], 16);
    csum[nf] += __shfl_xor(csum[nf], 32);
  }
  if (l < 16) {
    #pragma unroll
    for (int nf = 0; nf < 4; ++nf)
      denpart[((long)(qblk * 2 + wm) * B_ + b) * N_ +
              kblk * 256 + wn * 64 + nf * 16 + l] = csum[nf];
  }
}

// ------ K3: VsT8[b][d][k] = fp8(V[b][k][d] * 4096 / den[b][k]) ------
__global__ __launch_bounds__(256) void scale_transpose(
    const u16* __restrict__ Vb, const float* __restrict__ denpart,
    u8* __restrict__ VsT8) {
  const int b = blockIdx.z, k0 = blockIdx.y * 64, d0 = blockIdx.x * 64;
  __shared__ float tile[64][65];
  __shared__ float invden[64];
  const int t = threadIdx.x;
  if (t < 64) {
    float s = 0.f;
    for (int qs = 0; qs < 16; ++qs)
      s += denpart[((long)qs * B_ + b) * N_ + k0 + t];
    invden[t] = VS_SCALE / s;
  }
  __syncthreads();
  for (int idx = t; idx < 4096; idx += 256) {
    int kl = idx >> 6, dl = idx & 63;
    float v = bf2f(Vb[((long)b * N_ + k0 + kl) * D_ + d0 + dl]) * invden[kl];
    tile[dl][kl] = v;
  }
  __syncthreads();
  for (int idx = t; idx < 4096; idx += 256) {
    int dl = idx >> 6, kl = idx & 63;
    VsT8[((long)b * D_ + d0 + dl) * N_ + k0 + kl] = f2fp8(tile[dl][kl]);
  }
}

// ---------------- K4: out = (P8 @ Vs8)/4096 + xb ----------------
__global__ __launch_bounds__(512, 2) void pv_gemm(
    const u8* __restrict__ P8, const u8* __restrict__ VsT8,
    const u16* __restrict__ xb, float* __restrict__ out) {
  const int lin = blockIdx.x;
  const int b = lin & 7, inner = lin >> 3;
  const int qt = inner % 8, dt = inner / 8;
  const int q0 = qt * 256, d0 = dt * 256;

  f32x4 acc[8][4] = {};
  gemm256_fp8<N_ / 64>(P8 + ((long)b * N_ + q0) * N_, N_,
                       VsT8 + ((long)b * D_ + d0) * N_, N_, acc);

  const int l = threadIdx.x & 63, w = threadIdx.x >> 6;
  const int lr = l & 15, orow = (l >> 4) * 4;
  const int wm = w >> 2, wn = w & 3;
  const float inv_s = 1.0f / VS_SCALE;
  #pragma unroll
  for (int mf = 0; mf < 8; ++mf)
    #pragma unroll
    for (int nf = 0; nf < 4; ++nf) {
      int dd = d0 + wn * 64 + nf * 16 + lr;
      #pragma unroll
      for (int r = 0; r < 4; ++r) {
        int q = q0 + wm * 128 + mf * 16 + orow + r;
        long idx = ((long)b * N_ + q) * D_ + dd;
        out[idx] = acc[mf][nf][r] * inv_s + bf2f(xb[idx]);
      }
    }
}

extern "C" void kernel_launch(void* const* d_in, const int* in_sizes, int n_in,
                              void* d_out, int out_size, void* d_ws, size_t ws_size,
                              hipStream_t stream) {
  const float* x  = (const float*)d_in[0];
  const float* Wq = (const float*)d_in[1];
  const float* bq = (const float*)d_in[2];
  const float* Wk = (const float*)d_in[3];
  const float* bk = (const float*)d_in[4];
  const float* Wv = (const float*)d_in[5];
  const float* bv = (const float*)d_in[6];

  char* ws = (char*)d_ws;
  u16* xb  = (u16*)(ws + 0);                          // 25165824 B (live to pv)
  u16* wqb = (u16*)(ws + 25165824);
  u16* wkb = (u16*)(ws + 26345472);
  u16* wvb = (u16*)(ws + 27525120);
  u16* Qs  = (u16*)(ws + 28704768);
  u16* Kb  = (u16*)(ws + 53870592);
  u16* Vb  = (u16*)(ws + 79036416);
  u8*  VsT8 = (u8*)(ws + 104202240);                  // 12582912 B
  u8*  P8   = (u8*)(ws + 129368064);                  // 33554432 B
  float* denpart = (float*)(ws + 196476928);          // 1048576 B
  (void)in_sizes; (void)n_in; (void)out_size; (void)ws_size;

  cast_kernel<<<7008, 256, 0, stream>>>(x, Wq, Wk, Wv, xb, wqb, wkb, wvb);
  qkv_gemm<<<576, 512, 0, stream>>>(xb, wqb, wkb, wvb, bq, bk, bv, Qs, Kb, Vb);
  qk_exp<<<512, 512, 0, stream>>>(Qs, Kb, P8, denpart);
  scale_transpose<<<dim3(12, 32, 8), 256, 0, stream>>>(Vb, denpart, VsT8);
  pv_gemm<<<192, 512, 0, stream>>>(P8, VsT8, xb, (float*)d_out);
}

// Round 11
// 245.302 us; speedup vs baseline: 1.0095x; 1.0095x over previous
//
#include <hip/hip_runtime.h>
#include <stdint.h>

#define B_ 8
#define N_ 2048
#define D_ 768

typedef unsigned short u16;
typedef unsigned char u8;
typedef unsigned int u32;
typedef __attribute__((ext_vector_type(8))) short bf16x8;
typedef __attribute__((ext_vector_type(8))) unsigned short u16x8;
typedef __attribute__((ext_vector_type(4))) float f32x4;

static constexpr float INV_SCALE = 0.10825317547305482f; // 3/sqrt(768)
static constexpr float VS_SCALE = 4096.0f;               // Vs fp8 range scale

__device__ __forceinline__ u16 f2bf(float f) {
  union { float f; unsigned u; } v; v.f = f;
  return (u16)((v.u + 0x7FFFu + ((v.u >> 16) & 1u)) >> 16);
}
__device__ __forceinline__ float bf2f(u16 h) {
  union { unsigned u; float f; } v; v.u = ((unsigned)h) << 16;
  return v.f;
}
// OCP e4m3fn encode: RNE to 3-bit mantissa, clamp 448, FTZ below 2^-6.
__device__ __forceinline__ u8 f2fp8(float f) {
  union { float f; u32 u; } v; v.f = f;
  u32 s = (v.u >> 24) & 0x80u;
  u32 m = v.u & 0x7fffffffu;
  if (m >= 0x43E00000u) return (u8)(s | 0x7Eu);   // clamp to 448
  if (m < 0x3C800000u) return (u8)s;              // FTZ below 2^-6
  m += 0x000FFFFFu + ((m >> 20) & 1u);            // RNE at bit 20
  int e = (int)(m >> 23) - 127;
  if (e > 8) return (u8)(s | 0x7Eu);
  return (u8)(s | ((u32)(e + 7) << 3) | ((m >> 20) & 7u));
}
__device__ __forceinline__ f32x4 mfma16(bf16x8 a, bf16x8 b, f32x4 c) {
  return __builtin_amdgcn_mfma_f32_16x16x32_bf16(a, b, c, 0, 0, 0);
}
__device__ __forceinline__ f32x4 mfma8(long a, long b, f32x4 c) {
  return __builtin_amdgcn_mfma_f32_16x16x32_fp8_fp8(a, b, c, 0, 0, 0);
}
__device__ __forceinline__ void gl_lds16(const void* g, void* l) {
  __builtin_amdgcn_global_load_lds(
      (const __attribute__((address_space(1))) u32*)g,
      (__attribute__((address_space(3))) u32*)l, 16, 0, 0);
}

// ---------------- K0: cast x, Wq, Wk, Wv to bf16 ----------------
__global__ __launch_bounds__(256) void cast_kernel(
    const float* __restrict__ x, const float* __restrict__ wq,
    const float* __restrict__ wk, const float* __restrict__ wv,
    u16* __restrict__ xb, u16* __restrict__ wqb,
    u16* __restrict__ wkb, u16* __restrict__ wvb) {
  const long NX = (long)B_ * N_ * D_;
  const long NW = (long)D_ * D_;
  long i = ((long)blockIdx.x * 256 + threadIdx.x) * 8;
  const float* src; u16* dst; long off;
  if (i < NX) { src = x; dst = xb; off = i; }
  else {
    long j = i - NX;
    int seg = (int)(j / NW);
    off = j - (long)seg * NW;
    src = seg == 0 ? wq : (seg == 1 ? wk : wv);
    dst = seg == 0 ? wqb : (seg == 1 ? wkb : wvb);
  }
  float4 a = *(const float4*)(src + off);
  float4 b = *(const float4*)(src + off + 4);
  u16x8 o;
  o[0]=f2bf(a.x); o[1]=f2bf(a.y); o[2]=f2bf(a.z); o[3]=f2bf(a.w);
  o[4]=f2bf(b.x); o[5]=f2bf(b.y); o[6]=f2bf(b.z); o[7]=f2bf(b.w);
  *(u16x8*)(dst + off) = o;
}

// ==== bf16 256x256 BK=64 core (R9, unchanged): 8 waves, wave tile 128x64 ====
// 128 KB LDS -> 1 block/CU. Used by qk_exp (tail-free grid).
template<int NT>
__device__ __forceinline__ void gemm256(
    const u16* __restrict__ Ag, long lda,
    const u16* __restrict__ Bg, long ldb,
    f32x4 (&acc)[8][4]) {
  __shared__ u16 Ab[2][16384];
  __shared__ u16 Bb[2][16384];
  const int t_ = threadIdx.x, l = t_ & 63, w = t_ >> 6;
  const int lr = l & 15, kq = l >> 4;
  const int wm = w >> 2, wn = w & 3;
  const int arow = wm * 128, brow = wn * 64;
  const int s_rowl = l >> 3;
  const int s_sl = (l & 7) ^ (l >> 3);
  auto STAGE_A = [&](u16* As, int kt) {
    #pragma unroll
    for (int j = 0; j < 4; ++j) {
      const int row = j * 64 + w * 8 + s_rowl;
      gl_lds16(Ag + (long)row * lda + kt * 64 + s_sl * 8,
               As + ((j * 8192 + w * 1024) >> 1));
    }
  };
  auto STAGE_B = [&](u16* Bs, int kt) {
    #pragma unroll
    for (int j = 0; j < 4; ++j) {
      const int row = j * 64 + w * 8 + s_rowl;
      gl_lds16(Bg + (long)row * ldb + kt * 64 + s_sl * 8,
               Bs + ((j * 8192 + w * 1024) >> 1));
    }
  };

#define TILE(XA, XB, YA, YB, kt, DOST)                                       \
  {                                                                          \
    if (DOST) {                                                              \
      STAGE_A(YA, (kt) + 1);                                                 \
      asm volatile("s_waitcnt vmcnt(4)" ::: "memory");                       \
    } else {                                                                 \
      asm volatile("s_waitcnt vmcnt(0)" ::: "memory");                       \
    }                                                                        \
    __builtin_amdgcn_s_barrier();                                            \
    asm volatile("" ::: "memory");                                           \
    bf16x8 bf[4][2];                                                         \
    _Pragma("unroll")                                                        \
    for (int nf = 0; nf < 4; ++nf) {                                         \
      const int row = brow + nf * 16 + lr;                                   \
      _Pragma("unroll")                                                      \
      for (int ks = 0; ks < 2; ++ks)                                         \
        bf[nf][ks] = *(const bf16x8*)(XB + row * 64 +                        \
                        (((4 * ks + kq) ^ (lr & 7)) * 8));                   \
    }                                                                        \
    {                                                                        \
      bf16x8 af[4][2];                                                       \
      _Pragma("unroll")                                                      \
      for (int mf = 0; mf < 4; ++mf) {                                       \
        const int row = arow + mf * 16 + lr;                                 \
        _Pragma("unroll")                                                    \
        for (int ks = 0; ks < 2; ++ks)                                       \
          af[mf][ks] = *(const bf16x8*)(XA + row * 64 +                      \
                          (((4 * ks + kq) ^ (lr & 7)) * 8));                 \
      }                                                                      \
      __builtin_amdgcn_s_setprio(1);                                         \
      _Pragma("unroll")                                                      \
      for (int ks = 0; ks < 2; ++ks)                                         \
        _Pragma("unroll")                                                    \
        for (int mf = 0; mf < 4; ++mf)                                       \
          _Pragma("unroll")                                                  \
          for (int nf = 0; nf < 4; ++nf)                                     \
            acc[mf][nf] = mfma16(af[mf][ks], bf[nf][ks], acc[mf][nf]);       \
      __builtin_amdgcn_s_setprio(0);                                         \
    }                                                                        \
    if (DOST) STAGE_B(YB, (kt) + 1);                                         \
    {                                                                        \
      bf16x8 af[4][2];                                                       \
      _Pragma("unroll")                                                      \
      for (int mf = 0; mf < 4; ++mf) {                                       \
        const int row = arow + 64 + mf * 16 + lr;                            \
        _Pragma("unroll")                                                    \
        for (int ks = 0; ks < 2; ++ks)                                       \
          af[mf][ks] = *(const bf16x8*)(XA + row * 64 +                      \
                          (((4 * ks + kq) ^ (lr & 7)) * 8));                 \
      }                                                                      \
      __builtin_amdgcn_s_setprio(1);                                         \
      _Pragma("unroll")                                                      \
      for (int ks = 0; ks < 2; ++ks)                                         \
        _Pragma("unroll")                                                    \
        for (int mf = 0; mf < 4; ++mf)                                       \
          _Pragma("unroll")                                                  \
          for (int nf = 0; nf < 4; ++nf)                                     \
            acc[4 + mf][nf] = mfma16(af[mf][ks], bf[nf][ks], acc[4 + mf][nf]); \
      __builtin_amdgcn_s_setprio(0);                                         \
    }                                                                        \
    asm volatile("" ::: "memory");                                           \
    __builtin_amdgcn_s_barrier();                                            \
  }

  STAGE_A(Ab[0], 0);
  STAGE_B(Bb[0], 0);
  for (int t2 = 0; t2 < NT; t2 += 2) {
    TILE(Ab[0], Bb[0], Ab[1], Bb[1], t2, true)
    TILE(Ab[1], Bb[1], Ab[0], Bb[0], t2 + 1, (t2 + 2 < NT))
  }
#undef TILE
}

// ==== bf16 256x256 BK=32 core: 64 KB LDS -> 2 blocks/CU (qkv: tail-heavy
// grid, co-resident block fills barrier stalls). Same skeleton, counts
// halved: 2 gl_lds/stage, vmcnt 2/0, 12 ds_read_b128 per 32 MFMA.
// Rows are 64 B -> swizzle slot ^= (row>>1)&3 (all 8 bank-groups covered:
// bank = 16*(row&1) + 4*slot; (row&1,(row>>1)&3) distinct for lr 0..7).
template<int NT>
__device__ __forceinline__ void gemm256_bk32(
    const u16* __restrict__ Ag, long lda,
    const u16* __restrict__ Bg, long ldb,
    f32x4 (&acc)[8][4]) {
  __shared__ u16 Ab[2][8192];
  __shared__ u16 Bb[2][8192];
  const int t_ = threadIdx.x, l = t_ & 63, w = t_ >> 6;
  const int lr = l & 15, kq = l >> 4;
  const int wm = w >> 2, wn = w & 3;
  const int arow = wm * 128, brow = wn * 64;
  // stage: chunk j in {0,1}: base byte (w*2+j)*1024; lane l -> row
  // (w*2+j)*16 + (l>>2), phys slot l&3; source slot = (l&3)^((l>>3)&3)
  const int srow_l = l >> 2;
  const int s_sl = (l & 3) ^ ((l >> 3) & 3);
  auto STAGE_A = [&](u16* As, int kt) {
    #pragma unroll
    for (int j = 0; j < 2; ++j) {
      const int row = (w * 2 + j) * 16 + srow_l;
      gl_lds16(Ag + (long)row * lda + kt * 32 + s_sl * 8,
               As + (w * 2 + j) * 512);
    }
  };
  auto STAGE_B = [&](u16* Bs, int kt) {
    #pragma unroll
    for (int j = 0; j < 2; ++j) {
      const int row = (w * 2 + j) * 16 + srow_l;
      gl_lds16(Bg + (long)row * ldb + kt * 32 + s_sl * 8,
               Bs + (w * 2 + j) * 512);
    }
  };
  // read: u16 addr = row*32 + (kq ^ ((row>>1)&3))*8
#define FRB(BASE, ROW) \
  (*(const bf16x8*)((BASE) + (ROW) * 32 + ((kq ^ (((ROW) >> 1) & 3)) * 8)))

#define TILE32(XA, XB, YA, YB, kt, DOST)                                     \
  {                                                                          \
    if (DOST) {                                                              \
      STAGE_A(YA, (kt) + 1);                                                 \
      asm volatile("s_waitcnt vmcnt(2)" ::: "memory");                       \
    } else {                                                                 \
      asm volatile("s_waitcnt vmcnt(0)" ::: "memory");                       \
    }                                                                        \
    __builtin_amdgcn_s_barrier();                                            \
    asm volatile("" ::: "memory");                                           \
    bf16x8 bf[4];                                                            \
    _Pragma("unroll")                                                        \
    for (int nf = 0; nf < 4; ++nf)                                           \
      bf[nf] = FRB(XB, brow + nf * 16 + lr);                                 \
    {                                                                        \
      bf16x8 af[4];                                                          \
      _Pragma("unroll")                                                      \
      for (int mf = 0; mf < 4; ++mf)                                         \
        af[mf] = FRB(XA, arow + mf * 16 + lr);                               \
      __builtin_amdgcn_s_setprio(1);                                         \
      _Pragma("unroll")                                                      \
      for (int mf = 0; mf < 4; ++mf)                                         \
        _Pragma("unroll")                                                    \
        for (int nf = 0; nf < 4; ++nf)                                       \
          acc[mf][nf] = mfma16(af[mf], bf[nf], acc[mf][nf]);                 \
      __builtin_amdgcn_s_setprio(0);                                         \
    }                                                                        \
    if (DOST) STAGE_B(YB, (kt) + 1);                                         \
    {                                                                        \
      bf16x8 af[4];                                                          \
      _Pragma("unroll")                                                      \
      for (int mf = 0; mf < 4; ++mf)                                         \
        af[mf] = FRB(XA, arow + 64 + mf * 16 + lr);                          \
      __builtin_amdgcn_s_setprio(1);                                         \
      _Pragma("unroll")                                                      \
      for (int mf = 0; mf < 4; ++mf)                                         \
        _Pragma("unroll")                                                    \
        for (int nf = 0; nf < 4; ++nf)                                       \
          acc[4 + mf][nf] = mfma16(af[mf], bf[nf], acc[4 + mf][nf]);         \
      __builtin_amdgcn_s_setprio(0);                                         \
    }                                                                        \
    asm volatile("" ::: "memory");                                           \
    __builtin_amdgcn_s_barrier();                                            \
  }

  STAGE_A(Ab[0], 0);
  STAGE_B(Bb[0], 0);
  for (int t2 = 0; t2 < NT; t2 += 2) {
    TILE32(Ab[0], Bb[0], Ab[1], Bb[1], t2, true)
    TILE32(Ab[1], Bb[1], Ab[0], Bb[0], t2 + 1, (t2 + 2 < NT))
  }
#undef TILE32
#undef FRB
}

// ==== fp8 256x256 BK=64 core: swizzle FIXED to (row>>1)&3 ====
// 64-B rows: bank = 16*(row&1) + 4*slot; slot ^= (row>>1)&3 makes
// (row&1,(row>>1)&3) cover all 8 bank-groups -> 2-way (free).
// R10's ^(row&3) was 4-way-conflicted (14.16M SQ_LDS_BANK_CONFLICT).
template<int NT>
__device__ __forceinline__ void gemm256_fp8(
    const u8* __restrict__ Ag, long lda,
    const u8* __restrict__ Bg, long ldb,
    f32x4 (&acc)[8][4]) {
  __shared__ u8 Ab[2][16384];
  __shared__ u8 Bb[2][16384];
  const int t_ = threadIdx.x, l = t_ & 63, w = t_ >> 6;
  const int lr = l & 15, kq = l >> 4;
  const int wm = w >> 2, wn = w & 3;
  const int arow = wm * 128, brow = wn * 64;
  // stage: chunk ch = w*2+c: rows [16ch,16ch+16); lane l -> row 16ch+(l>>2),
  // phys s16 = l&3; source s16 = (l&3) ^ ((row>>1)&3) = (l&3)^((l>>3)&3)
  const int srow_l = l >> 2;
  const int s16src = (l & 3) ^ ((l >> 3) & 3);
  auto STAGE_A = [&](u8* As, int kt) {
    #pragma unroll
    for (int c = 0; c < 2; ++c) {
      const int ch = w * 2 + c;
      gl_lds16(Ag + (long)(ch * 16 + srow_l) * lda + kt * 64 + s16src * 16,
               As + ch * 1024);
    }
  };
  auto STAGE_B = [&](u8* Bs, int kt) {
    #pragma unroll
    for (int c = 0; c < 2; ++c) {
      const int ch = w * 2 + c;
      gl_lds16(Bg + (long)(ch * 16 + srow_l) * ldb + kt * 64 + s16src * 16,
               Bs + ch * 1024);
    }
  };
  // fragment byte addr: row*64 + ((k8>>1)^((row>>1)&3))*16 + (k8&1)*8
#define FR8(BASE, ROW, KS)                                                   \
  (*(const long*)((BASE) + (ROW) * 64 +                                      \
      ((((4 * (KS) + kq) >> 1) ^ (((ROW) >> 1) & 3)) * 16) +                 \
      ((4 * (KS) + kq) & 1) * 8))

#define TILE8(XA, XB, YA, YB, kt, DOST)                                      \
  {                                                                          \
    if (DOST) {                                                              \
      STAGE_A(YA, (kt) + 1);                                                 \
      asm volatile("s_waitcnt vmcnt(2)" ::: "memory");                       \
    } else {                                                                 \
      asm volatile("s_waitcnt vmcnt(0)" ::: "memory");                       \
    }                                                                        \
    __builtin_amdgcn_s_barrier();                                            \
    asm volatile("" ::: "memory");                                           \
    long bfr[4][2];                                                          \
    _Pragma("unroll")                                                        \
    for (int nf = 0; nf < 4; ++nf) {                                         \
      const int row = brow + nf * 16 + lr;                                   \
      _Pragma("unroll")                                                      \
      for (int ks = 0; ks < 2; ++ks)                                         \
        bfr[nf][ks] = FR8(XB, row, ks);                                      \
    }                                                                        \
    {                                                                        \
      long afr[4][2];                                                        \
      _Pragma("unroll")                                                      \
      for (int mf = 0; mf < 4; ++mf) {                                       \
        const int row = arow + mf * 16 + lr;                                 \
        _Pragma("unroll")                                                    \
        for (int ks = 0; ks < 2; ++ks)                                       \
          afr[mf][ks] = FR8(XA, row, ks);                                    \
      }                                                                      \
      __builtin_amdgcn_s_setprio(1);                                         \
      _Pragma("unroll")                                                      \
      for (int ks = 0; ks < 2; ++ks)                                         \
        _Pragma("unroll")                                                    \
        for (int mf = 0; mf < 4; ++mf)                                       \
          _Pragma("unroll")                                                  \
          for (int nf = 0; nf < 4; ++nf)                                     \
            acc[mf][nf] = mfma8(afr[mf][ks], bfr[nf][ks], acc[mf][nf]);      \
      __builtin_amdgcn_s_setprio(0);                                         \
    }                                                                        \
    if (DOST) STAGE_B(YB, (kt) + 1);                                         \
    {                                                                        \
      long afr[4][2];                                                        \
      _Pragma("unroll")                                                      \
      for (int mf = 0; mf < 4; ++mf) {                                       \
        const int row = arow + 64 + mf * 16 + lr;                            \
        _Pragma("unroll")                                                    \
        for (int ks = 0; ks < 2; ++ks)                                       \
          afr[mf][ks] = FR8(XA, row, ks);                                    \
      }                                                                      \
      __builtin_amdgcn_s_setprio(1);                                         \
      _Pragma("unroll")                                                      \
      for (int ks = 0; ks < 2; ++ks)                                         \
        _Pragma("unroll")                                                    \
        for (int mf = 0; mf < 4; ++mf)                                       \
          _Pragma("unroll")                                                  \
          for (int nf = 0; nf < 4; ++nf)                                     \
            acc[4 + mf][nf] = mfma8(afr[mf][ks], bfr[nf][ks], acc[4 + mf][nf]); \
      __builtin_amdgcn_s_setprio(0);                                         \
    }                                                                        \
    asm volatile("" ::: "memory");                                           \
    __builtin_amdgcn_s_barrier();                                            \
  }

  STAGE_A(Ab[0], 0);
  STAGE_B(Bb[0], 0);
  for (int t2 = 0; t2 < NT; t2 += 2) {
    TILE8(Ab[0], Bb[0], Ab[1], Bb[1], t2, true)
    TILE8(Ab[1], Bb[1], Ab[0], Bb[0], t2 + 1, (t2 + 2 < NT))
  }
#undef TILE8
#undef FR8
}

// ---------------- K1: Q/K/V = x @ W^T + b (Q scaled) ----------------
__global__ __launch_bounds__(512, 2) void qkv_gemm(
    const u16* __restrict__ xb,
    const u16* __restrict__ wq, const u16* __restrict__ wk, const u16* __restrict__ wv,
    const float* __restrict__ bq, const float* __restrict__ bk, const float* __restrict__ bv,
    u16* __restrict__ Qs, u16* __restrict__ Kb, u16* __restrict__ Vb) {
  const int lin = blockIdx.x;
  const int xcd = lin & 7, inner = lin >> 3;
  const int rt = xcd * 8 + (inner & 7);
  const int rest = inner >> 3;
  const int ct = rest % 3, mat = rest / 3;
  const u16* W = mat == 0 ? wq : (mat == 1 ? wk : wv);
  const float* bias = mat == 0 ? bq : (mat == 1 ? bk : bv);
  u16* out = mat == 0 ? Qs : (mat == 1 ? Kb : Vb);
  const float scl = mat == 0 ? INV_SCALE : 1.0f;
  const int rbase = rt * 256, cbase = ct * 256;

  f32x4 acc[8][4] = {};
  gemm256_bk32<D_ / 32>(xb + (long)rbase * D_, D_, W + (long)cbase * D_, D_, acc);

  const int l = threadIdx.x & 63, w = threadIdx.x >> 6;
  const int lr = l & 15, orow = (l >> 4) * 4;
  const int wm = w >> 2, wn = w & 3;
  #pragma unroll
  for (int mf = 0; mf < 8; ++mf)
    #pragma unroll
    for (int nf = 0; nf < 4; ++nf) {
      int col = cbase + wn * 64 + nf * 16 + lr;
      float bc = bias[col];
      #pragma unroll
      for (int r = 0; r < 4; ++r) {
        int row = rbase + wm * 128 + mf * 16 + orow + r;
        out[(long)row * D_ + col] = f2bf((acc[mf][nf][r] + bc) * scl);
      }
    }
}

// ---------------- K2: P8 = fp8(exp(Q.K^T)), den partials ----------------
__global__ __launch_bounds__(512, 2) void qk_exp(
    const u16* __restrict__ Qs, const u16* __restrict__ Kb,
    u8* __restrict__ P8, float* __restrict__ denpart) {
  const int lin = blockIdx.x;
  const int b = lin & 7, inner = lin >> 3;
  const int kblk = inner & 7, qblk = inner >> 3;

  f32x4 acc[8][4] = {};
  gemm256<D_ / 64>(Qs + ((long)b * N_ + qblk * 256) * D_, D_,
                   Kb + ((long)b * N_ + kblk * 256) * D_, D_, acc);

  const int tt = threadIdx.x, l = tt & 63, w = tt >> 6;
  const int lr = l & 15, orow = (l >> 4) * 4;
  const int wm = w >> 2, wn = w & 3;
  float csum[4] = {0.f, 0.f, 0.f, 0.f};
  #pragma unroll
  for (int mf = 0; mf < 8; ++mf)
    #pragma unroll
    for (int nf = 0; nf < 4; ++nf) {
      long kk = kblk * 256 + wn * 64 + nf * 16 + lr;
      #pragma unroll
      for (int r = 0; r < 4; ++r) {
        long q = qblk * 256 + wm * 128 + mf * 16 + orow + r;
        float e = __expf(acc[mf][nf][r]);
        P8[((long)b * N_ + q) * N_ + kk] = f2fp8(e);
        csum[nf] += e;
      }
    }
  #pragma unroll
  for (int nf = 0; nf < 4; ++nf) {
    csum[nf] += __shfl_xor(csum[nf], 16);
    csum[nf] += __shfl_xor(csum[nf], 32);
  }
  if (l < 16) {
    #pragma unroll
    for (int nf = 0; nf < 4; ++nf)
      denpart[((long)(qblk * 2 + wm) * B_ + b) * N_ +
              kblk * 256 + wn * 64 + nf * 16 + l] = csum[nf];
  }
}

// ------ K3: VsT8[b][d][k] = fp8(V[b][k][d] * 4096 / den[b][k]) ------
__global__ __launch_bounds__(256) void scale_transpose(
    const u16* __restrict__ Vb, const float* __restrict__ denpart,
    u8* __restrict__ VsT8) {
  const int b = blockIdx.z, k0 = blockIdx.y * 64, d0 = blockIdx.x * 64;
  __shared__ float tile[64][65];
  __shared__ float invden[64];
  const int t = threadIdx.x;
  if (t < 64) {
    float s = 0.f;
    for (int qs = 0; qs < 16; ++qs)
      s += denpart[((long)qs * B_ + b) * N_ + k0 + t];
    invden[t] = VS_SCALE / s;
  }
  __syncthreads();
  for (int idx = t; idx < 4096; idx += 256) {
    int kl = idx >> 6, dl = idx & 63;
    float v = bf2f(Vb[((long)b * N_ + k0 + kl) * D_ + d0 + dl]) * invden[kl];
    tile[dl][kl] = v;
  }
  __syncthreads();
  for (int idx = t; idx < 4096; idx += 256) {
    int dl = idx >> 6, kl = idx & 63;
    VsT8[((long)b * D_ + d0 + dl) * N_ + k0 + kl] = f2fp8(tile[dl][kl]);
  }
}

// ---------------- K4: out = (P8 @ Vs8)/4096 + xb ----------------
__global__ __launch_bounds__(512, 2) void pv_gemm(
    const u8* __restrict__ P8, const u8* __restrict__ VsT8,
    const u16* __restrict__ xb, float* __restrict__ out) {
  const int lin = blockIdx.x;
  const int b = lin & 7, inner = lin >> 3;
  const int qt = inner % 8, dt = inner / 8;
  const int q0 = qt * 256, d0 = dt * 256;

  f32x4 acc[8][4] = {};
  gemm256_fp8<N_ / 64>(P8 + ((long)b * N_ + q0) * N_, N_,
                       VsT8 + ((long)b * D_ + d0) * N_, N_, acc);

  const int l = threadIdx.x & 63, w = threadIdx.x >> 6;
  const int lr = l & 15, orow = (l >> 4) * 4;
  const int wm = w >> 2, wn = w & 3;
  const float inv_s = 1.0f / VS_SCALE;
  #pragma unroll
  for (int mf = 0; mf < 8; ++mf)
    #pragma unroll
    for (int nf = 0; nf < 4; ++nf) {
      int dd = d0 + wn * 64 + nf * 16 + lr;
      #pragma unroll
      for (int r = 0; r < 4; ++r) {
        int q = q0 + wm * 128 + mf * 16 + orow + r;
        long idx = ((long)b * N_ + q) * D_ + dd;
        out[idx] = acc[mf][nf][r] * inv_s + bf2f(xb[idx]);
      }
    }
}

extern "C" void kernel_launch(void* const* d_in, const int* in_sizes, int n_in,
                              void* d_out, int out_size, void* d_ws, size_t ws_size,
                              hipStream_t stream) {
  const float* x  = (const float*)d_in[0];
  const float* Wq = (const float*)d_in[1];
  const float* bq = (const float*)d_in[2];
  const float* Wk = (const float*)d_in[3];
  const float* bk = (const float*)d_in[4];
  const float* Wv = (const float*)d_in[5];
  const float* bv = (const float*)d_in[6];

  char* ws = (char*)d_ws;
  u16* xb  = (u16*)(ws + 0);                          // 25165824 B (live to pv)
  u16* wqb = (u16*)(ws + 25165824);
  u16* wkb = (u16*)(ws + 26345472);
  u16* wvb = (u16*)(ws + 27525120);
  u16* Qs  = (u16*)(ws + 28704768);
  u16* Kb  = (u16*)(ws + 53870592);
  u16* Vb  = (u16*)(ws + 79036416);
  u8*  VsT8 = (u8*)(ws + 104202240);                  // 12582912 B
  u8*  P8   = (u8*)(ws + 129368064);                  // 33554432 B
  float* denpart = (float*)(ws + 196476928);          // 1048576 B
  (void)in_sizes; (void)n_in; (void)out_size; (void)ws_size;

  cast_kernel<<<7008, 256, 0, stream>>>(x, Wq, Wk, Wv, xb, wqb, wkb, wvb);
  qkv_gemm<<<576, 512, 0, stream>>>(xb, wqb, wkb, wvb, bq, bk, bv, Qs, Kb, Vb);
  qk_exp<<<512, 512, 0, stream>>>(Qs, Kb, P8, denpart);
  scale_transpose<<<dim3(12, 32, 8), 256, 0, stream>>>(Vb, denpart, VsT8);
  pv_gemm<<<192, 512, 0, stream>>>(P8, VsT8, xb, (float*)d_out);
}

// Round 12
// 209.846 us; speedup vs baseline: 1.1800x; 1.1690x over previous
//
#include <hip/hip_runtime.h>
#include <stdint.h>

#define B_ 8
#define N_ 2048
#define D_ 768

typedef unsigned short u16;
typedef unsigned int u32;
typedef __attribute__((ext_vector_type(8))) short bf16x8;
typedef __attribute__((ext_vector_type(8))) unsigned short u16x8;
typedef __attribute__((ext_vector_type(4))) float f32x4;

static constexpr float INV_SCALE = 0.10825317547305482f; // 3/sqrt(768)

__device__ __forceinline__ u16 f2bf(float f) {
  union { float f; unsigned u; } v; v.f = f;
  return (u16)((v.u + 0x7FFFu + ((v.u >> 16) & 1u)) >> 16);
}
__device__ __forceinline__ float bf2f(u16 h) {
  union { unsigned u; float f; } v; v.u = ((unsigned)h) << 16;
  return v.f;
}
__device__ __forceinline__ f32x4 mfma16(bf16x8 a, bf16x8 b, f32x4 c) {
  return __builtin_amdgcn_mfma_f32_16x16x32_bf16(a, b, c, 0, 0, 0);
}
__device__ __forceinline__ void gl_lds16(const void* g, void* l) {
  __builtin_amdgcn_global_load_lds(
      (const __attribute__((address_space(1))) u32*)g,
      (__attribute__((address_space(3))) u32*)l, 16, 0, 0);
}

// ---------------- K0: cast x, Wq, Wk, Wv to bf16 ----------------
__global__ __launch_bounds__(256) void cast_kernel(
    const float* __restrict__ x, const float* __restrict__ wq,
    const float* __restrict__ wk, const float* __restrict__ wv,
    u16* __restrict__ xb, u16* __restrict__ wqb,
    u16* __restrict__ wkb, u16* __restrict__ wvb) {
  const long NX = (long)B_ * N_ * D_;
  const long NW = (long)D_ * D_;
  long i = ((long)blockIdx.x * 256 + threadIdx.x) * 8;
  const float* src; u16* dst; long off;
  if (i < NX) { src = x; dst = xb; off = i; }
  else {
    long j = i - NX;
    int seg = (int)(j / NW);
    off = j - (long)seg * NW;
    src = seg == 0 ? wq : (seg == 1 ? wk : wv);
    dst = seg == 0 ? wqb : (seg == 1 ? wkb : wvb);
  }
  float4 a = *(const float4*)(src + off);
  float4 b = *(const float4*)(src + off + 4);
  u16x8 o;
  o[0]=f2bf(a.x); o[1]=f2bf(a.y); o[2]=f2bf(a.z); o[3]=f2bf(a.w);
  o[4]=f2bf(b.x); o[5]=f2bf(b.y); o[6]=f2bf(b.z); o[7]=f2bf(b.w);
  *(u16x8*)(dst + off) = o;
}

// ==== bf16 256 x (NF*64) BK=64 core: 8 waves (2M x 4N), wave tile 128x(NF*16)
// R9-verified skeleton, N-width templated (NF=4 -> 256 cols, NF=3 -> 192).
//   ph0: STAGE_A(t+1) [4 gl_lds]; vmcnt(4) -> tile t fully landed
//        (outstanding = A(t+1)4 + B(t+1)NF + A(t+2)4, drain to 4);
//        barrier; read bf[NF][2] + af0[4][2]; MFMA rows 0-63.
//   ph1: STAGE_B(t+1) [NF gl_lds]; read af1; MFMA rows 64-127; barrier.
// Counted vmcnt never 0 mid-loop. Swizzle both sides (verified R3-R11):
// phys 16B-slot = logical ^ (row&7); source pre-swizzled to match.
template<int NT, int NF>
__device__ __forceinline__ void gemm256(
    const u16* __restrict__ Ag, long lda,
    const u16* __restrict__ Bg, long ldb,
    f32x4 (&acc)[8][NF]) {
  __shared__ u16 Ab[2][16384];
  __shared__ u16 Bb[2][NF * 4096];
  const int t_ = threadIdx.x, l = t_ & 63, w = t_ >> 6;
  const int lr = l & 15, kq = l >> 4;
  const int wm = w >> 2, wn = w & 3;
  const int arow = wm * 128, brow = wn * (NF * 16);
  const int s_rowl = l >> 3;
  const int s_sl = (l & 7) ^ (l >> 3);
  auto STAGE_A = [&](u16* As, int kt) {
    #pragma unroll
    for (int j = 0; j < 4; ++j) {
      const int row = j * 64 + w * 8 + s_rowl;
      gl_lds16(Ag + (long)row * lda + kt * 64 + s_sl * 8,
               As + ((j * 8192 + w * 1024) >> 1));
    }
  };
  auto STAGE_B = [&](u16* Bs, int kt) {
    #pragma unroll
    for (int j = 0; j < NF; ++j) {
      const int row = j * 64 + w * 8 + s_rowl;
      gl_lds16(Bg + (long)row * ldb + kt * 64 + s_sl * 8,
               Bs + ((j * 8192 + w * 1024) >> 1));
    }
  };

#define TILE(XA, XB, YA, YB, kt, DOST)                                       \
  {                                                                          \
    if (DOST) {                                                              \
      STAGE_A(YA, (kt) + 1);                                                 \
      asm volatile("s_waitcnt vmcnt(4)" ::: "memory");                       \
    } else {                                                                 \
      asm volatile("s_waitcnt vmcnt(0)" ::: "memory");                       \
    }                                                                        \
    __builtin_amdgcn_s_barrier();                                            \
    asm volatile("" ::: "memory");                                           \
    bf16x8 bf[NF][2];                                                        \
    _Pragma("unroll")                                                        \
    for (int nf = 0; nf < NF; ++nf) {                                        \
      const int row = brow + nf * 16 + lr;                                   \
      _Pragma("unroll")                                                      \
      for (int ks = 0; ks < 2; ++ks)                                         \
        bf[nf][ks] = *(const bf16x8*)(XB + row * 64 +                        \
                        (((4 * ks + kq) ^ (lr & 7)) * 8));                   \
    }                                                                        \
    {                                                                        \
      bf16x8 af[4][2];                                                       \
      _Pragma("unroll")                                                      \
      for (int mf = 0; mf < 4; ++mf) {                                       \
        const int row = arow + mf * 16 + lr;                                 \
        _Pragma("unroll")                                                    \
        for (int ks = 0; ks < 2; ++ks)                                       \
          af[mf][ks] = *(const bf16x8*)(XA + row * 64 +                      \
                          (((4 * ks + kq) ^ (lr & 7)) * 8));                 \
      }                                                                      \
      __builtin_amdgcn_s_setprio(1);                                         \
      _Pragma("unroll")                                                      \
      for (int ks = 0; ks < 2; ++ks)                                         \
        _Pragma("unroll")                                                    \
        for (int mf = 0; mf < 4; ++mf)                                       \
          _Pragma("unroll")                                                  \
          for (int nf = 0; nf < NF; ++nf)                                    \
            acc[mf][nf] = mfma16(af[mf][ks], bf[nf][ks], acc[mf][nf]);       \
      __builtin_amdgcn_s_setprio(0);                                         \
    }                                                                        \
    if (DOST) STAGE_B(YB, (kt) + 1);                                         \
    {                                                                        \
      bf16x8 af[4][2];                                                       \
      _Pragma("unroll")                                                      \
      for (int mf = 0; mf < 4; ++mf) {                                       \
        const int row = arow + 64 + mf * 16 + lr;                            \
        _Pragma("unroll")                                                    \
        for (int ks = 0; ks < 2; ++ks)                                       \
          af[mf][ks] = *(const bf16x8*)(XA + row * 64 +                      \
                          (((4 * ks + kq) ^ (lr & 7)) * 8));                 \
      }                                                                      \
      __builtin_amdgcn_s_setprio(1);                                         \
      _Pragma("unroll")                                                      \
      for (int ks = 0; ks < 2; ++ks)                                         \
        _Pragma("unroll")                                                    \
        for (int mf = 0; mf < 4; ++mf)                                       \
          _Pragma("unroll")                                                  \
          for (int nf = 0; nf < NF; ++nf)                                    \
            acc[4 + mf][nf] = mfma16(af[mf][ks], bf[nf][ks], acc[4 + mf][nf]); \
      __builtin_amdgcn_s_setprio(0);                                         \
    }                                                                        \
    asm volatile("" ::: "memory");                                           \
    __builtin_amdgcn_s_barrier();                                            \
  }

  STAGE_A(Ab[0], 0);
  STAGE_B(Bb[0], 0);
  for (int t2 = 0; t2 < NT; t2 += 2) {
    TILE(Ab[0], Bb[0], Ab[1], Bb[1], t2, true)
    TILE(Ab[1], Bb[1], Ab[0], Bb[0], t2 + 1, (t2 + 2 < NT))
  }
#undef TILE
}

// ---------------- K1: Q/K/V = x @ W^T + b (Q scaled) ----------------
// tile 256x192 -> grid 768 = 64 rt x 12 ct = 3.0 EXACT rounds on 256 CUs.
// XCD = rt-band (8 rt x 256 rows x 768 = 3.1 MB xb slice, L2-fit).
__global__ __launch_bounds__(512, 1) void qkv_gemm(
    const u16* __restrict__ xb,
    const u16* __restrict__ wq, const u16* __restrict__ wk, const u16* __restrict__ wv,
    const float* __restrict__ bq, const float* __restrict__ bk, const float* __restrict__ bv,
    u16* __restrict__ Qs, u16* __restrict__ Kb, u16* __restrict__ Vb) {
  const int lin = blockIdx.x;
  const int xcd = lin & 7, inner = lin >> 3;          // inner: 0..95
  const int rt = xcd * 8 + (inner & 7);
  const int ct = inner >> 3;                          // 0..11 over 3 mats
  const int mat = ct >> 2;
  const u16* W = mat == 0 ? wq : (mat == 1 ? wk : wv);
  const float* bias = mat == 0 ? bq : (mat == 1 ? bk : bv);
  u16* out = mat == 0 ? Qs : (mat == 1 ? Kb : Vb);
  const float scl = mat == 0 ? INV_SCALE : 1.0f;
  const int rbase = rt * 256, cbase = (ct & 3) * 192;

  f32x4 acc[8][3] = {};
  gemm256<D_ / 64, 3>(xb + (long)rbase * D_, D_, W + (long)cbase * D_, D_, acc);

  const int l = threadIdx.x & 63, w = threadIdx.x >> 6;
  const int lr = l & 15, orow = (l >> 4) * 4;
  const int wm = w >> 2, wn = w & 3;
  #pragma unroll
  for (int mf = 0; mf < 8; ++mf)
    #pragma unroll
    for (int nf = 0; nf < 3; ++nf) {
      int col = cbase + wn * 48 + nf * 16 + lr;
      float bc = bias[col];
      #pragma unroll
      for (int r = 0; r < 4; ++r) {
        int row = rbase + wm * 128 + mf * 16 + orow + r;
        out[(long)row * D_ + col] = f2bf((acc[mf][nf][r] + bc) * scl);
      }
    }
}

// ---------------- K2: P = exp(Q.K^T) bf16, den partials ----------------
// grid 512 = 2.0 exact rounds (unchanged, ~1120 TF); XCD = one b.
__global__ __launch_bounds__(512, 1) void qk_exp(
    const u16* __restrict__ Qs, const u16* __restrict__ Kb,
    u16* __restrict__ P, float* __restrict__ denpart) {
  const int lin = blockIdx.x;
  const int b = lin & 7, inner = lin >> 3;
  const int kblk = inner & 7, qblk = inner >> 3;

  f32x4 acc[8][4] = {};
  gemm256<D_ / 64, 4>(Qs + ((long)b * N_ + qblk * 256) * D_, D_,
                      Kb + ((long)b * N_ + kblk * 256) * D_, D_, acc);

  const int tt = threadIdx.x, l = tt & 63, w = tt >> 6;
  const int lr = l & 15, orow = (l >> 4) * 4;
  const int wm = w >> 2, wn = w & 3;
  float csum[4] = {0.f, 0.f, 0.f, 0.f};
  #pragma unroll
  for (int mf = 0; mf < 8; ++mf)
    #pragma unroll
    for (int nf = 0; nf < 4; ++nf) {
      long kk = kblk * 256 + wn * 64 + nf * 16 + lr;
      #pragma unroll
      for (int r = 0; r < 4; ++r) {
        long q = qblk * 256 + wm * 128 + mf * 16 + orow + r;
        float e = __expf(acc[mf][nf][r]);
        u16 pe = f2bf(e);
        P[((long)b * N_ + q) * N_ + kk] = pe;
        csum[nf] += bf2f(pe);
      }
    }
  #pragma unroll
  for (int nf = 0; nf < 4; ++nf) {
    csum[nf] += __shfl_xor(csum[nf], 16);
    csum[nf] += __shfl_xor(csum[nf], 32);
  }
  if (l < 16) {
    #pragma unroll
    for (int nf = 0; nf < 4; ++nf)
      denpart[((long)(qblk * 2 + wm) * B_ + b) * N_ +
              kblk * 256 + wn * 64 + nf * 16 + l] = csum[nf];
  }
}

// ---------------- K3: VsT[b][d][k] = V[b][k][d] / den[b][k] ----------------
__global__ __launch_bounds__(256) void scale_transpose(
    const u16* __restrict__ Vb, const float* __restrict__ denpart,
    u16* __restrict__ VsT) {
  const int b = blockIdx.z, k0 = blockIdx.y * 64, d0 = blockIdx.x * 64;
  __shared__ float tile[64][65];
  __shared__ float invden[64];
  const int t = threadIdx.x;
  if (t < 64) {
    float s = 0.f;
    for (int qs = 0; qs < 16; ++qs)
      s += denpart[((long)qs * B_ + b) * N_ + k0 + t];
    invden[t] = 1.0f / s;
  }
  __syncthreads();
  for (int idx = t; idx < 4096; idx += 256) {
    int kl = idx >> 6, dl = idx & 63;
    float v = bf2f(Vb[((long)b * N_ + k0 + kl) * D_ + d0 + dl]) * invden[kl];
    tile[dl][kl] = v;
  }
  __syncthreads();
  for (int idx = t; idx < 4096; idx += 256) {
    int dl = idx >> 6, kl = idx & 63;
    VsT[((long)b * D_ + d0 + dl) * N_ + k0 + kl] = f2bf(tile[dl][kl]);
  }
}

// ---------------- K4: out = P @ Vs + xb (bf16 residual) ----------------
// tile 256x192 -> grid 256 = 8 qt x 4 dt x 8 b = 1.0 EXACT round, all CUs.
// XCD = one b (32 blocks): VsT_b (3 MB) L2-hot, P_b streamed once.
__global__ __launch_bounds__(512, 1) void pv_gemm(
    const u16* __restrict__ P, const u16* __restrict__ VsT,
    const u16* __restrict__ xb, float* __restrict__ out) {
  const int lin = blockIdx.x;
  const int b = lin & 7, inner = lin >> 3;            // inner: 0..31
  const int qt = inner & 7, dt = inner >> 3;          // 8 qt x 4 dt
  const int q0 = qt * 256, d0 = dt * 192;

  f32x4 acc[8][3] = {};
  gemm256<N_ / 64, 3>(P + ((long)b * N_ + q0) * N_, N_,
                      VsT + ((long)b * D_ + d0) * N_, N_, acc);

  const int l = threadIdx.x & 63, w = threadIdx.x >> 6;
  const int lr = l & 15, orow = (l >> 4) * 4;
  const int wm = w >> 2, wn = w & 3;
  #pragma unroll
  for (int mf = 0; mf < 8; ++mf)
    #pragma unroll
    for (int nf = 0; nf < 3; ++nf) {
      int dd = d0 + wn * 48 + nf * 16 + lr;
      #pragma unroll
      for (int r = 0; r < 4; ++r) {
        int q = q0 + wm * 128 + mf * 16 + orow + r;
        long idx = ((long)b * N_ + q) * D_ + dd;
        out[idx] = acc[mf][nf][r] + bf2f(xb[idx]);
      }
    }
}

extern "C" void kernel_launch(void* const* d_in, const int* in_sizes, int n_in,
                              void* d_out, int out_size, void* d_ws, size_t ws_size,
                              hipStream_t stream) {
  const float* x  = (const float*)d_in[0];
  const float* Wq = (const float*)d_in[1];
  const float* bq = (const float*)d_in[2];
  const float* Wk = (const float*)d_in[3];
  const float* bk = (const float*)d_in[4];
  const float* Wv = (const float*)d_in[5];
  const float* bv = (const float*)d_in[6];

  char* ws = (char*)d_ws;
  u16* xb  = (u16*)(ws + 0);                          // 25165824 B (live to pv)
  u16* wqb = (u16*)(ws + 25165824);
  u16* wkb = (u16*)(ws + 26345472);
  u16* wvb = (u16*)(ws + 27525120);
  u16* Qs  = (u16*)(ws + 28704768);
  u16* Kb  = (u16*)(ws + 53870592);
  u16* Vb  = (u16*)(ws + 79036416);
  u16* VsT = (u16*)(ws + 104202240);                  // 25165824 B
  u16* P   = (u16*)(ws + 129368064);                  // 67108864 B
  float* denpart = (float*)(ws + 196476928);          // 1048576 B
  (void)in_sizes; (void)n_in; (void)out_size; (void)ws_size;

  cast_kernel<<<7008, 256, 0, stream>>>(x, Wq, Wk, Wv, xb, wqb, wkb, wvb);
  qkv_gemm<<<768, 512, 0, stream>>>(xb, wqb, wkb, wvb, bq, bk, bv, Qs, Kb, Vb);
  qk_exp<<<512, 512, 0, stream>>>(Qs, Kb, P, denpart);
  scale_transpose<<<dim3(12, 32, 8), 256, 0, stream>>>(Vb, denpart, VsT);
  pv_gemm<<<256, 512, 0, stream>>>(P, VsT, xb, (float*)d_out);
}